// Round 4
// baseline (928.094 us; speedup 1.0000x reference)
//
#include <hip/hip_runtime.h>
#include <hip/hip_bf16.h>

#define NQ     131072       // 32*4096 queries
#define KC     1024         // codes
#define DIM    64
#define MARGIN 3e-4f        // f32 top-2 margin below which we re-score in f64
#define FLAGF  2048.0f      // flag offset in f32 idx slot

// ---------- K1: distances + argmin + flag; writes FINAL f32 idx ----------
__global__ __launch_bounds__(256) void k_assign(const float* __restrict__ inp,
                                                const float* __restrict__ emb,
                                                float* __restrict__ idx_out) {
    __shared__ float4 etile[128 * 16];   // raw 128 codes x 64 f32 = 32 KB
    __shared__ float  ss[128];           // sum of squares per raw row
    __shared__ float  en2s[128];         // sum(ehat^2)
    __shared__ float  scl[128];          // 1/max(||e||,eps)
    const int tid = threadIdx.x;
    const int q = blockIdx.x * 256 + tid;

    float x[DIM];
    const float4* xin = reinterpret_cast<const float4*>(inp + (size_t)q * DIM);
    #pragma unroll
    for (int i = 0; i < 16; ++i) {
        float4 t = xin[i];
        x[4*i+0] = t.x; x[4*i+1] = t.y; x[4*i+2] = t.z; x[4*i+3] = t.w;
    }
    float sx = 0.f;
    #pragma unroll
    for (int i = 0; i < DIM; ++i) sx += x[i] * x[i];
    float den = fmaxf(sqrtf(sx), 1e-12f);
    float A = 0.f;
    #pragma unroll
    for (int i = 0; i < DIM; ++i) { x[i] = x[i] / den; A += x[i] * x[i]; }
    #pragma unroll
    for (int i = 0; i < DIM; ++i) x[i] *= 2.0f;        // 2*flat_n

    float best = 3.4e38f, best2 = 3.4e38f;
    int   bidx = 0;

    for (int t = 0; t < 8; ++t) {                      // 8 tiles of 128 codes
        __syncthreads();
        if (tid < 128) ss[tid] = 0.f;
        __syncthreads();
        const float4* src = reinterpret_cast<const float4*>(emb + (size_t)t * 128 * DIM);
        #pragma unroll
        for (int i = 0; i < 8; ++i) {
            int f = tid + i * 256;                     // float4 index in tile
            float4 v = src[f];
            etile[f] = v;
            atomicAdd(&ss[f >> 4], v.x*v.x + v.y*v.y + v.z*v.z + v.w*v.w);
        }
        __syncthreads();
        if (tid < 128) {
            float s = 1.0f / fmaxf(sqrtf(ss[tid]), 1e-12f);
            scl[tid]  = s;
            en2s[tid] = ss[tid] * s * s;
        }
        __syncthreads();

        for (int c = 0; c < 128; c += 4) {
            const float4* e0 = &etile[(c + 0) * 16];
            const float4* e1 = &etile[(c + 1) * 16];
            const float4* e2 = &etile[(c + 2) * 16];
            const float4* e3 = &etile[(c + 3) * 16];
            float a0 = 0.f, a1 = 0.f, a2 = 0.f, a3 = 0.f;
            #pragma unroll
            for (int i = 0; i < 16; ++i) {
                float4 v0 = e0[i], v1 = e1[i], v2 = e2[i], v3 = e3[i];
                a0 = fmaf(x[4*i+0], v0.x, a0); a0 = fmaf(x[4*i+1], v0.y, a0);
                a0 = fmaf(x[4*i+2], v0.z, a0); a0 = fmaf(x[4*i+3], v0.w, a0);
                a1 = fmaf(x[4*i+0], v1.x, a1); a1 = fmaf(x[4*i+1], v1.y, a1);
                a1 = fmaf(x[4*i+2], v1.z, a1); a1 = fmaf(x[4*i+3], v1.w, a1);
                a2 = fmaf(x[4*i+0], v2.x, a2); a2 = fmaf(x[4*i+1], v2.y, a2);
                a2 = fmaf(x[4*i+2], v2.z, a2); a2 = fmaf(x[4*i+3], v2.w, a2);
                a3 = fmaf(x[4*i+0], v3.x, a3); a3 = fmaf(x[4*i+1], v3.y, a3);
                a3 = fmaf(x[4*i+2], v3.z, a3); a3 = fmaf(x[4*i+3], v3.w, a3);
            }
            float d[4];
            d[0] = (A + en2s[c + 0]) - scl[c + 0] * a0;
            d[1] = (A + en2s[c + 1]) - scl[c + 1] * a1;
            d[2] = (A + en2s[c + 2]) - scl[c + 2] * a2;
            d[3] = (A + en2s[c + 3]) - scl[c + 3] * a3;
            int kbase = t * 128 + c;
            #pragma unroll
            for (int j = 0; j < 4; ++j) {              // sequential: first-min
                if (d[j] < best)       { best2 = best; best = d[j]; bidx = kbase + j; }
                else if (d[j] < best2) { best2 = d[j]; }
            }
        }
    }

    float v = (float)bidx;
    if (best2 - best < MARGIN) v += FLAGF;             // ambiguous -> f64 rescue
    idx_out[q] = v;
}

// ---------- K2: f64 rescore of flagged queries (block-local list) ----------
__global__ __launch_bounds__(256) void k_rescue(const float* __restrict__ inp,
                                                const float* __restrict__ emb,
                                                float* __restrict__ idx_out) {
    __shared__ int    lst[256];
    __shared__ int    cnt;
    __shared__ double xh[DIM];
    __shared__ double Ash;
    __shared__ double sd[256];
    __shared__ int    si[256];
    const int tid = threadIdx.x;
    const int q0  = blockIdx.x * 256;

    if (tid == 0) cnt = 0;
    __syncthreads();
    if (idx_out[q0 + tid] >= FLAGF) { int s = atomicAdd(&cnt, 1); lst[s] = q0 + tid; }
    __syncthreads();
    const int n = cnt;

    for (int j = 0; j < n; ++j) {
        const int q = lst[j];
        if (tid < 64) {
            double xv = (double)inp[(size_t)q * DIM + tid];
            double s = xv * xv;
            #pragma unroll
            for (int off = 32; off; off >>= 1) s += __shfl_xor(s, off);
            double dn = fmax(sqrt(s), 1e-12);
            double h  = xv / dn;
            xh[tid] = h;
            double a = h * h;
            #pragma unroll
            for (int off = 32; off; off >>= 1) a += __shfl_xor(a, off);
            if (tid == 0) Ash = a;
        }
        __syncthreads();
        const double A = Ash;

        double bd = 1e300; int bi = 1 << 30;
        for (int c = tid; c < KC; c += 256) {
            const float* e = emb + (size_t)c * DIM;
            double s2 = 0.0;
            for (int i = 0; i < DIM; ++i) { double ev = (double)e[i]; s2 += ev * ev; }
            double inv = 1.0 / fmax(sqrt(s2), 1e-12);
            double b2 = 0.0, dot = 0.0;
            for (int i = 0; i < DIM; ++i) {
                double eh = (double)e[i] * inv;
                b2  += eh * eh;
                dot += xh[i] * eh;
            }
            double d = (A + b2) - 2.0 * dot;
            if (d < bd || (d == bd && c < bi)) { bd = d; bi = c; }
        }
        sd[tid] = bd; si[tid] = bi;
        __syncthreads();
        if (tid == 0) {
            double B = sd[0]; int I = si[0];
            for (int i = 1; i < 256; ++i)
                if (sd[i] < B || (sd[i] == B && si[i] < I)) { B = sd[i]; I = si[i]; }
            idx_out[q] = (float)I;                     // final, flag cleared
        }
        __syncthreads();
    }
}

// ---------- K3: gather (f32 out) + sum((q-f)^2) ----------
__global__ __launch_bounds__(256) void k_gather_loss(const float* __restrict__ inp,
                                                     const float* __restrict__ emb,
                                                     const float* __restrict__ idx_out,
                                                     float* __restrict__ qout,
                                                     float* __restrict__ loss) {
    const int gid = blockIdx.x * 256 + threadIdx.x;    // 524288 threads
    float lsum = 0.f;
    for (int e4 = gid; e4 < NQ * 16; e4 += 524288) {   // float4 tiles of output
        int   qi = e4 >> 4;
        int   d4 = e4 & 15;
        int   k  = ((int)idx_out[qi]) & (KC - 1);
        float4 qv = reinterpret_cast<const float4*>(emb + (size_t)k * DIM)[d4];
        float4 fv = reinterpret_cast<const float4*>(inp)[e4];
        float ux = qv.x - fv.x, uy = qv.y - fv.y, uz = qv.z - fv.z, uw = qv.w - fv.w;
        lsum += ux*ux + uy*uy + uz*uz + uw*uw;
        reinterpret_cast<float4*>(qout)[e4] = qv;      // STE fwd == quantized
    }
    #pragma unroll
    for (int off = 32; off; off >>= 1) lsum += __shfl_xor(lsum, off);
    __shared__ float wsum[4];
    int wid = threadIdx.x >> 6, lane = threadIdx.x & 63;
    if (lane == 0) wsum[wid] = lsum;
    __syncthreads();
    if (threadIdx.x == 0)
        atomicAdd(loss, (wsum[0] + wsum[1]) + (wsum[2] + wsum[3]));
}

// ---------- K4: histogram + perplexity/usage/vq_loss (single block) ----------
__global__ __launch_bounds__(1024) void k_stats(const float* __restrict__ idx_out,
                                                float* __restrict__ out3) {
    __shared__ int hist[KC];
    const int t = threadIdx.x;
    hist[t] = 0;
    __syncthreads();
    for (int q = t; q < NQ; q += 1024)
        atomicAdd(&hist[((int)idx_out[q]) & (KC - 1)], 1);
    __syncthreads();
    int c = hist[t];
    float p    = (float)c * (1.0f / (float)NQ);        // exact (pow2 divisor)
    float ent  = p * logf(p + 1e-10f);
    float used = (c > 0) ? 1.0f : 0.0f;
    #pragma unroll
    for (int off = 32; off; off >>= 1) {
        ent  += __shfl_xor(ent, off);
        used += __shfl_xor(used, off);
    }
    __shared__ float se[16], su[16];
    int w = t >> 6, l = t & 63;
    if (l == 0) { se[w] = ent; su[w] = used; }
    __syncthreads();
    if (t == 0) {
        float E = 0.f, U = 0.f;
        #pragma unroll
        for (int i = 0; i < 16; ++i) { E += se[i]; U += su[i]; }
        float L = out3[0];                             // loss accumulated here
        out3[0] = L * 1.25f / 8388608.0f;              // vq_loss (q + 0.25*e)
        out3[1] = expf(-E);                            // perplexity
        out3[2] = U * (1.0f / 1024.0f);                // codebook_usage
    }
}

// ---------- launch ----------
// d_out is FLOAT32 (8519683 elems): [0,8388608) quantized | [8388608,8519680) idx
//                                   | [8519680..2] vq_loss, perplexity, usage
// idx slots are written final-form by k_assign (flag +2048 cleared by k_rescue;
// downstream consumers mask &1023). out3[0] doubles as the f32 loss accumulator
// until k_stats finalizes it. d_ws: UNUSED.
extern "C" void kernel_launch(void* const* d_in, const int* in_sizes, int n_in,
                              void* d_out, int out_size, void* d_ws, size_t ws_size,
                              hipStream_t stream) {
    const float* inp = (const float*)d_in[0];   // [32,4096,64] f32
    const float* emb = (const float*)d_in[1];   // [1024,64] f32

    float* qout    = (float*)d_out;
    float* idx_out = (float*)d_out + 8388608;
    float* out3    = (float*)d_out + 8519680;

    hipMemsetAsync(out3, 0, 4, stream);         // zero the loss accumulator
    hipLaunchKernelGGL(k_assign,      dim3(512),  dim3(256),  0, stream, inp, emb, idx_out);
    hipLaunchKernelGGL(k_rescue,      dim3(512),  dim3(256),  0, stream, inp, emb, idx_out);
    hipLaunchKernelGGL(k_gather_loss, dim3(2048), dim3(256),  0, stream,
                       inp, emb, idx_out, qout, out3);
    hipLaunchKernelGGL(k_stats,       dim3(1),    dim3(1024), 0, stream, idx_out, out3);
}

// Round 5
// 511.923 us; speedup vs baseline: 1.8130x; 1.8130x over previous
//
#include <hip/hip_runtime.h>
#include <hip/hip_bf16.h>

#define NQ     131072       // 32*4096 queries
#define KC     1024         // codes
#define DIM    64
#define MARGIN 4e-4f        // top-2 margin below which we re-score in f64
#define FLAGF  2048.0f      // flag offset in f32 idx slot

typedef __attribute__((ext_vector_type(8))) short  s8bf;   // 8 bf16 (4 VGPRs)
typedef __attribute__((ext_vector_type(4))) float  f32x4;  // MFMA acc

union BF8 { s8bf v; unsigned short u[8]; };

__device__ __forceinline__ unsigned short f2bf_u(float f) {
    union { __hip_bfloat16 h; unsigned short u; } cv;
    cv.h = __float2bfloat16(f);
    return cv.u;
}
__device__ __forceinline__ float bfu2f(unsigned short u) {
    union { __hip_bfloat16 h; unsigned short u; } cv;
    cv.u = u;
    return __bfloat162float(cv.h);
}

// ---------- K0: prep codes -> normalized bf16 hi/lo in MFMA B-frag layout ----------
// B-frag for tile t (16 codes), K-step s, comp c(0=hi,1=lo):
//   lane = col + 16*((k>>3)&3), elem j = k&7;  frag index F = t*4 + s*2 + c
//   u16 index = (F*64 + lane)*8 + j
__global__ __launch_bounds__(256) void k_prep(const float* __restrict__ emb,
                                              unsigned short* __restrict__ wB,
                                              float* __restrict__ wE2) {
    int c = blockIdx.x * 256 + threadIdx.x;    // 4 blocks -> 1024 codes
    if (c >= KC) return;
    float e[DIM];
    const float4* ep = reinterpret_cast<const float4*>(emb + (size_t)c * DIM);
    #pragma unroll
    for (int i = 0; i < 16; ++i) {
        float4 t = ep[i];
        e[4*i+0] = t.x; e[4*i+1] = t.y; e[4*i+2] = t.z; e[4*i+3] = t.w;
    }
    float s = 0.f;
    #pragma unroll
    for (int i = 0; i < DIM; ++i) s += e[i] * e[i];
    float inv = 1.0f / fmaxf(sqrtf(s), 1e-12f);
    float e2 = 0.f;
    const int t = c >> 4, col = c & 15;
    #pragma unroll
    for (int k = 0; k < DIM; ++k) {
        float h = e[k] * inv;
        e2 += h * h;
        unsigned short hi = f2bf_u(h);
        unsigned short lo = f2bf_u(h - bfu2f(hi));
        int s_ = k >> 5, g = (k >> 3) & 3, j = k & 7;
        int ln = col + 16 * g;
        wB[((t*4 + s_*2 + 0) * 64 + ln) * 8 + j] = hi;
        wB[((t*4 + s_*2 + 1) * 64 + ln) * 8 + j] = lo;
    }
    wE2[c] = e2;
}

// ---------- K1: MFMA distances + argmin + margin flag ----------
// block = 256 thr (4 waves); wave handles 64 queries (4 M-subtiles) x all 1024 codes
__global__ __launch_bounds__(256) void k_assign(const float* __restrict__ inp,
                                                const unsigned short* __restrict__ wB,
                                                const float* __restrict__ wE2,
                                                float* __restrict__ idx_out) {
    __shared__ s8bf  Bt[2048];     // 32 KB: one chunk = 8 tiles x 4 frags x 64 lanes
    __shared__ float e2s[KC];      // 4 KB
    const int tid  = threadIdx.x;
    const int lane = tid & 63, wv = tid >> 6;
    const int col  = lane & 15, g  = lane >> 4;
    const int qbase = blockIdx.x * 256 + wv * 64;

    for (int i = tid; i < KC; i += 256) e2s[i] = wE2[i];

    // Build A fragments: lane holds query (qbase+16s+col), dims [8g,8g+8) & [32+8g,+8)
    BF8 ah[4][2], al[4][2];
    #pragma unroll
    for (int s = 0; s < 4; ++s) {
        const float4* q4 = reinterpret_cast<const float4*>(inp + (size_t)(qbase + 16*s + col) * DIM);
        float4 xa = q4[2*g], xb = q4[2*g + 1], ya = q4[8 + 2*g], yb = q4[9 + 2*g];
        float x[16] = { xa.x, xa.y, xa.z, xa.w, xb.x, xb.y, xb.z, xb.w,
                        ya.x, ya.y, ya.z, ya.w, yb.x, yb.y, yb.z, yb.w };
        float sq = 0.f;
        #pragma unroll
        for (int i = 0; i < 16; ++i) sq += x[i] * x[i];
        sq += __shfl_xor(sq, 16);
        sq += __shfl_xor(sq, 32);
        float inv = 1.0f / fmaxf(sqrtf(sq), 1e-12f);
        #pragma unroll
        for (int i = 0; i < 8; ++i) {
            float h0 = x[i] * inv, h1 = x[8 + i] * inv;
            unsigned short hi0 = f2bf_u(h0);
            unsigned short hi1 = f2bf_u(h1);
            ah[s][0].u[i] = hi0;  al[s][0].u[i] = f2bf_u(h0 - bfu2f(hi0));
            ah[s][1].u[i] = hi1;  al[s][1].u[i] = f2bf_u(h1 - bfu2f(hi1));
        }
    }

    float best[4][4], best2[4][4];
    int   bidx[4][4];
    #pragma unroll
    for (int s = 0; s < 4; ++s)
        #pragma unroll
        for (int r = 0; r < 4; ++r) { best[s][r] = 3.4e38f; best2[s][r] = 3.4e38f; bidx[s][r] = 0; }

    for (int ch = 0; ch < 8; ++ch) {           // 8 chunks of 128 codes
        __syncthreads();
        const float4* src = reinterpret_cast<const float4*>(wB) + (size_t)ch * 2048;
        float4* dst = reinterpret_cast<float4*>(Bt);
        #pragma unroll
        for (int i = 0; i < 8; ++i) dst[tid + i * 256] = src[tid + i * 256];
        __syncthreads();

        for (int nt = 0; nt < 8; ++nt) {       // 8 tiles of 16 codes
            s8bf bh0 = Bt[(nt*4 + 0) * 64 + lane];
            s8bf bl0 = Bt[(nt*4 + 1) * 64 + lane];
            s8bf bh1 = Bt[(nt*4 + 2) * 64 + lane];
            s8bf bl1 = Bt[(nt*4 + 3) * 64 + lane];
            const int gt = ch * 8 + nt;
            const int code = gt * 16 + col;
            const float e2 = e2s[code];
            #pragma unroll
            for (int s = 0; s < 4; ++s) {
                f32x4 acc = {0.f, 0.f, 0.f, 0.f};
                acc = __builtin_amdgcn_mfma_f32_16x16x32_bf16(ah[s][0].v, bh0, acc, 0, 0, 0);
                acc = __builtin_amdgcn_mfma_f32_16x16x32_bf16(ah[s][1].v, bh1, acc, 0, 0, 0);
                acc = __builtin_amdgcn_mfma_f32_16x16x32_bf16(ah[s][0].v, bl0, acc, 0, 0, 0);
                acc = __builtin_amdgcn_mfma_f32_16x16x32_bf16(ah[s][1].v, bl1, acc, 0, 0, 0);
                acc = __builtin_amdgcn_mfma_f32_16x16x32_bf16(al[s][0].v, bh0, acc, 0, 0, 0);
                acc = __builtin_amdgcn_mfma_f32_16x16x32_bf16(al[s][1].v, bh1, acc, 0, 0, 0);
                #pragma unroll
                for (int r = 0; r < 4; ++r) {  // lane's col = code; rows = 4 queries
                    float v = fmaf(-2.0f, acc[r], e2);
                    if (v < best[s][r]) { best2[s][r] = best[s][r]; best[s][r] = v; bidx[s][r] = code; }
                    else                { best2[s][r] = fminf(best2[s][r], v); }
                }
            }
        }
    }

    // reduce (best,best2,idx) across the 16 lanes of each row-group; write idx
    #pragma unroll
    for (int s = 0; s < 4; ++s) {
        #pragma unroll
        for (int off = 1; off < 16; off <<= 1) {
            #pragma unroll
            for (int r = 0; r < 4; ++r) {
                float ob  = __shfl_xor(best[s][r],  off);
                float ob2 = __shfl_xor(best2[s][r], off);
                int   oi  = __shfl_xor(bidx[s][r],  off);
                if (ob < best[s][r]) {
                    best2[s][r] = fminf(best[s][r], ob2);
                    best[s][r]  = ob;
                    bidx[s][r]  = oi;
                } else {
                    best2[s][r] = fminf(best2[s][r], ob);
                }
            }
        }
        if (col < 4) {                         // r = col; C row = 4*g + r
            int   r  = col;
            int   qq = qbase + 16*s + 4*g + r;
            float fl = (best2[s][r] - best[s][r] < MARGIN) ? FLAGF : 0.0f;
            idx_out[qq] = (float)bidx[s][r] + fl;
        }
    }
}

// ---------- K2: f64 rescore of flagged queries (proven, unchanged) ----------
__global__ __launch_bounds__(256) void k_rescue(const float* __restrict__ inp,
                                                const float* __restrict__ emb,
                                                float* __restrict__ idx_out) {
    __shared__ int    lst[256];
    __shared__ int    cnt;
    __shared__ double xh[DIM];
    __shared__ double Ash;
    __shared__ double sd[256];
    __shared__ int    si[256];
    const int tid = threadIdx.x;
    const int q0  = blockIdx.x * 256;

    if (tid == 0) cnt = 0;
    __syncthreads();
    if (idx_out[q0 + tid] >= FLAGF) { int s = atomicAdd(&cnt, 1); lst[s] = q0 + tid; }
    __syncthreads();
    const int n = cnt;

    for (int j = 0; j < n; ++j) {
        const int q = lst[j];
        if (tid < 64) {
            double xv = (double)inp[(size_t)q * DIM + tid];
            double s = xv * xv;
            #pragma unroll
            for (int off = 32; off; off >>= 1) s += __shfl_xor(s, off);
            double dn = fmax(sqrt(s), 1e-12);
            double h  = xv / dn;
            xh[tid] = h;
            double a = h * h;
            #pragma unroll
            for (int off = 32; off; off >>= 1) a += __shfl_xor(a, off);
            if (tid == 0) Ash = a;
        }
        __syncthreads();
        const double A = Ash;

        double bd = 1e300; int bi = 1 << 30;
        for (int c = tid; c < KC; c += 256) {
            const float* e = emb + (size_t)c * DIM;
            double s2 = 0.0;
            for (int i = 0; i < DIM; ++i) { double ev = (double)e[i]; s2 += ev * ev; }
            double inv = 1.0 / fmax(sqrt(s2), 1e-12);
            double b2 = 0.0, dot = 0.0;
            for (int i = 0; i < DIM; ++i) {
                double eh = (double)e[i] * inv;
                b2  += eh * eh;
                dot += xh[i] * eh;
            }
            double d = (A + b2) - 2.0 * dot;
            if (d < bd || (d == bd && c < bi)) { bd = d; bi = c; }
        }
        sd[tid] = bd; si[tid] = bi;
        __syncthreads();
        if (tid == 0) {
            double B = sd[0]; int I = si[0];
            for (int i = 1; i < 256; ++i)
                if (sd[i] < B || (sd[i] == B && si[i] < I)) { B = sd[i]; I = si[i]; }
            idx_out[q] = (float)I;             // final, flag cleared
        }
        __syncthreads();
    }
}

// ---------- K3: gather (f32 out) + sum((q-f)^2) ----------
__global__ __launch_bounds__(256) void k_gather_loss(const float* __restrict__ inp,
                                                     const float* __restrict__ emb,
                                                     const float* __restrict__ idx_out,
                                                     float* __restrict__ qout,
                                                     float* __restrict__ loss) {
    const int gid = blockIdx.x * 256 + threadIdx.x;    // 524288 threads
    float lsum = 0.f;
    for (int e4 = gid; e4 < NQ * 16; e4 += 524288) {
        int   qi = e4 >> 4;
        int   d4 = e4 & 15;
        int   k  = ((int)idx_out[qi]) & (KC - 1);
        float4 qv = reinterpret_cast<const float4*>(emb + (size_t)k * DIM)[d4];
        float4 fv = reinterpret_cast<const float4*>(inp)[e4];
        float ux = qv.x - fv.x, uy = qv.y - fv.y, uz = qv.z - fv.z, uw = qv.w - fv.w;
        lsum += ux*ux + uy*uy + uz*uz + uw*uw;
        reinterpret_cast<float4*>(qout)[e4] = qv;
    }
    #pragma unroll
    for (int off = 32; off; off >>= 1) lsum += __shfl_xor(lsum, off);
    __shared__ float wsum[4];
    int wid = threadIdx.x >> 6, lane = threadIdx.x & 63;
    if (lane == 0) wsum[wid] = lsum;
    __syncthreads();
    if (threadIdx.x == 0)
        atomicAdd(loss, (wsum[0] + wsum[1]) + (wsum[2] + wsum[3]));
}

// ---------- K4: parallel histogram into ws counts ----------
__global__ __launch_bounds__(256) void k_hist(const float* __restrict__ idx_out,
                                              int* __restrict__ counts) {
    __shared__ int h[KC];
    const int tid = threadIdx.x;
    for (int i = tid; i < KC; i += 256) h[i] = 0;
    __syncthreads();
    const int qb = blockIdx.x * 2048;                  // grid 64 -> exactly NQ
    for (int i = tid; i < 2048; i += 256)
        atomicAdd(&h[((int)idx_out[qb + i]) & (KC - 1)], 1);
    __syncthreads();
    for (int i = tid; i < KC; i += 256) {
        int v = h[i];
        if (v) atomicAdd(&counts[i], v);
    }
}

// ---------- K5: perplexity / usage / vq_loss ----------
__global__ __launch_bounds__(1024) void k_stats2(const int* __restrict__ counts,
                                                 float* __restrict__ out3) {
    int t = threadIdx.x;
    int c = counts[t];
    float p    = (float)c * (1.0f / (float)NQ);
    float ent  = p * logf(p + 1e-10f);
    float used = (c > 0) ? 1.0f : 0.0f;
    #pragma unroll
    for (int off = 32; off; off >>= 1) {
        ent  += __shfl_xor(ent, off);
        used += __shfl_xor(used, off);
    }
    __shared__ float se[16], su[16];
    int w = t >> 6, l = t & 63;
    if (l == 0) { se[w] = ent; su[w] = used; }
    __syncthreads();
    if (t == 0) {
        float E = 0.f, U = 0.f;
        #pragma unroll
        for (int i = 0; i < 16; ++i) { E += se[i]; U += su[i]; }
        float L = out3[0];                             // loss accumulated here
        out3[0] = L * 1.25f / 8388608.0f;              // vq_loss (q + 0.25*e)
        out3[1] = expf(-E);                            // perplexity
        out3[2] = U * (1.0f / 1024.0f);                // codebook_usage
    }
}

// ---------- launch ----------
// d_out (f32, 8519683): [0,8388608) quantized | [8388608,8519680) idx | 3 scalars
// d_ws: counts[1024] @0 | wB u16[131072] @4096 (256KB) | wE2 f32[1024] @266240
extern "C" void kernel_launch(void* const* d_in, const int* in_sizes, int n_in,
                              void* d_out, int out_size, void* d_ws, size_t ws_size,
                              hipStream_t stream) {
    const float* inp = (const float*)d_in[0];   // [32,4096,64] f32
    const float* emb = (const float*)d_in[1];   // [1024,64] f32

    float* qout    = (float*)d_out;
    float* idx_out = (float*)d_out + 8388608;
    float* out3    = (float*)d_out + 8519680;

    int*            counts = (int*)d_ws;
    unsigned short* wB     = (unsigned short*)((char*)d_ws + 4096);
    float*          wE2    = (float*)((char*)d_ws + 266240);

    hipMemsetAsync(d_ws, 0, 4096, stream);      // counts
    hipMemsetAsync(out3, 0, 4, stream);         // loss accumulator
    hipLaunchKernelGGL(k_prep,        dim3(4),    dim3(256),  0, stream, emb, wB, wE2);
    hipLaunchKernelGGL(k_assign,      dim3(512),  dim3(256),  0, stream, inp, wB, wE2, idx_out);
    hipLaunchKernelGGL(k_rescue,      dim3(512),  dim3(256),  0, stream, inp, emb, idx_out);
    hipLaunchKernelGGL(k_gather_loss, dim3(2048), dim3(256),  0, stream,
                       inp, emb, idx_out, qout, out3);
    hipLaunchKernelGGL(k_hist,        dim3(64),   dim3(256),  0, stream, idx_out, counts);
    hipLaunchKernelGGL(k_stats2,      dim3(1),    dim3(1024), 0, stream, counts, out3);
}

// Round 6
// 226.331 us; speedup vs baseline: 4.1006x; 2.2618x over previous
//
#include <hip/hip_runtime.h>
#include <hip/hip_bf16.h>

#define NQ       131072     // 32*4096 queries
#define KC       1024       // codes
#define DIM      64
#define MARGIN_P 6.5e-4f    // packed-gap margin: 4e-4 true + 2*2.44e-4 quantization
#define FLAGF    2048.0f    // flag offset in f32 idx slot

typedef __attribute__((ext_vector_type(8))) short  s8bf;   // 8 bf16 (4 VGPRs)
typedef __attribute__((ext_vector_type(4))) float  f32x4;  // MFMA acc

union BF8 { s8bf v; unsigned short u[8]; };

__device__ __forceinline__ unsigned short f2bf_u(float f) {
    union { __hip_bfloat16 h; unsigned short u; } cv;
    cv.h = __float2bfloat16(f);
    return cv.u;
}
__device__ __forceinline__ float bfu2f(unsigned short u) {
    union { __hip_bfloat16 h; unsigned short u; } cv;
    cv.u = u;
    return __bfloat162float(cv.h);
}
__device__ __forceinline__ void gl_lds16(const float4* g, float4* l) {
    __builtin_amdgcn_global_load_lds(
        (const __attribute__((address_space(1))) unsigned int*)g,
        (__attribute__((address_space(3))) unsigned int*)l, 16, 0, 0);
}

// ---------- K0: prep codes -> bf16 hi/lo B-frags + e2p (f32) + f64 rescue consts ----------
// B-frag for tile t (16 codes), K-half s, comp c(0=hi,1=lo): F = t*4 + s*2 + c
//   lane = col + 16*((k>>3)&3), elem j = k&7;  u16 index = (F*64 + lane)*8 + j
__global__ __launch_bounds__(256) void k_prep(const float* __restrict__ emb,
                                              unsigned short* __restrict__ wB,
                                              float* __restrict__ wE2p,
                                              double* __restrict__ wInvD,
                                              double* __restrict__ wB2D) {
    int c = blockIdx.x * 256 + threadIdx.x;    // 4 blocks -> 1024 codes
    if (c >= KC) return;
    float e[DIM];
    const float4* ep = reinterpret_cast<const float4*>(emb + (size_t)c * DIM);
    #pragma unroll
    for (int i = 0; i < 16; ++i) {
        float4 t = ep[i];
        e[4*i+0] = t.x; e[4*i+1] = t.y; e[4*i+2] = t.z; e[4*i+3] = t.w;
    }
    // f32 path (identical numerics to the passing round-5 kernel)
    float s = 0.f;
    #pragma unroll
    for (int i = 0; i < DIM; ++i) s += e[i] * e[i];
    float inv = 1.0f / fmaxf(sqrtf(s), 1e-12f);
    float e2 = 0.f;
    const int t = c >> 4, col = c & 15;
    #pragma unroll
    for (int k = 0; k < DIM; ++k) {
        float h = e[k] * inv;
        e2 += h * h;
        unsigned short hi = f2bf_u(h);
        unsigned short lo = f2bf_u(h - bfu2f(hi));
        int s_ = k >> 5, g = (k >> 3) & 3, j = k & 7;
        int ln = col + 16 * g;
        wB[((t*4 + s_*2 + 0) * 64 + ln) * 8 + j] = hi;
        wB[((t*4 + s_*2 + 1) * 64 + ln) * 8 + j] = lo;
    }
    wE2p[c] = e2 + 2.0f;                       // pre-biased for positive pack
    // f64 rescue constants
    double sd = 0.0;
    #pragma unroll
    for (int i = 0; i < DIM; ++i) sd += (double)e[i] * (double)e[i];
    double invd = 1.0 / fmax(sqrt(sd), 1e-12);
    wInvD[c] = invd;
    wB2D[c]  = sd * invd * invd;
}

// ---------- K1: MFMA distances + packed-int argmin + margin flag ----------
// block = 256 thr (4 waves); wave handles 32 queries x all 1024 codes
__global__ __launch_bounds__(256) void k_assign(const float* __restrict__ inp,
                                                const unsigned short* __restrict__ wB,
                                                const float* __restrict__ wE2p,
                                                float* __restrict__ idx_out) {
    __shared__ s8bf  Bt[2048];     // 32 KB: chunk = 8 tiles x 4 frags x 64 lanes
    __shared__ float e2ps[KC];     // 4 KB (e2+2)
    const int tid  = threadIdx.x;
    const int lane = tid & 63, wv = tid >> 6;
    const int col  = lane & 15, g  = lane >> 4;
    const int qbase = blockIdx.x * 128 + wv * 32;

    for (int i = tid; i < KC; i += 256) e2ps[i] = wE2p[i];

    // A fragments: lane holds query (qbase+16s+col), dims [8g,8g+8) & [32+8g,+8)
    BF8 ah[2][2], al[2][2];
    #pragma unroll
    for (int s = 0; s < 2; ++s) {
        const float4* q4 = reinterpret_cast<const float4*>(inp + (size_t)(qbase + 16*s + col) * DIM);
        float4 xa = q4[2*g], xb = q4[2*g + 1], ya = q4[8 + 2*g], yb = q4[9 + 2*g];
        float x[16] = { xa.x, xa.y, xa.z, xa.w, xb.x, xb.y, xb.z, xb.w,
                        ya.x, ya.y, ya.z, ya.w, yb.x, yb.y, yb.z, yb.w };
        float sq = 0.f;
        #pragma unroll
        for (int i = 0; i < 16; ++i) sq += x[i] * x[i];
        sq += __shfl_xor(sq, 16);
        sq += __shfl_xor(sq, 32);
        float inv = 1.0f / fmaxf(sqrtf(sq), 1e-12f);
        #pragma unroll
        for (int i = 0; i < 8; ++i) {
            float h0 = x[i] * inv, h1 = x[8 + i] * inv;
            unsigned short hi0 = f2bf_u(h0);
            unsigned short hi1 = f2bf_u(h1);
            ah[s][0].u[i] = hi0;  al[s][0].u[i] = f2bf_u(h0 - bfu2f(hi0));
            ah[s][1].u[i] = hi1;  al[s][1].u[i] = f2bf_u(h1 - bfu2f(hi1));
        }
    }

    int best[2][4], best2[2][4];
    #pragma unroll
    for (int s = 0; s < 2; ++s)
        #pragma unroll
        for (int r = 0; r < 4; ++r) { best[s][r] = 0x7FFFFFFF; best2[s][r] = 0x7FFFFFFF; }

    for (int ch = 0; ch < 8; ++ch) {           // 8 chunks of 128 codes
        __syncthreads();
        const float4* src = reinterpret_cast<const float4*>(wB) + (size_t)ch * 2048;
        float4* dst = reinterpret_cast<float4*>(Bt);
        #pragma unroll
        for (int i = 0; i < 8; ++i) {
            int idx = i * 256 + tid;
            gl_lds16(&src[idx], &dst[idx]);    // linear: base + lane*16 (m97 pattern)
        }
        __syncthreads();                       // drains vmcnt before use

        for (int nt = 0; nt < 8; ++nt) {       // 8 tiles of 16 codes
            s8bf bh0 = Bt[(nt*4 + 0) * 64 + lane];
            s8bf bl0 = Bt[(nt*4 + 1) * 64 + lane];
            s8bf bh1 = Bt[(nt*4 + 2) * 64 + lane];
            s8bf bl1 = Bt[(nt*4 + 3) * 64 + lane];
            const int code = ch * 128 + nt * 16 + col;
            const float e2p = e2ps[code];
            #pragma unroll
            for (int s = 0; s < 2; ++s) {
                f32x4 acc = {0.f, 0.f, 0.f, 0.f};
                acc = __builtin_amdgcn_mfma_f32_16x16x32_bf16(ah[s][0].v, bh0, acc, 0, 0, 0);
                acc = __builtin_amdgcn_mfma_f32_16x16x32_bf16(ah[s][1].v, bh1, acc, 0, 0, 0);
                acc = __builtin_amdgcn_mfma_f32_16x16x32_bf16(ah[s][0].v, bl0, acc, 0, 0, 0);
                acc = __builtin_amdgcn_mfma_f32_16x16x32_bf16(ah[s][1].v, bl1, acc, 0, 0, 0);
                acc = __builtin_amdgcn_mfma_f32_16x16x32_bf16(al[s][0].v, bh0, acc, 0, 0, 0);
                acc = __builtin_amdgcn_mfma_f32_16x16x32_bf16(al[s][1].v, bh1, acc, 0, 0, 0);
                #pragma unroll
                for (int r = 0; r < 4; ++r) {
                    float dp = fmaf(-2.0f, acc[r], e2p);          // in (0.9, 5.1) > 0
                    int p = (__float_as_int(dp) & 0xFFFFFC00) | code;
                    int mn = min(best[s][r], p);
                    int mx = max(best[s][r], p);
                    best[s][r]  = mn;
                    best2[s][r] = min(best2[s][r], mx);
                }
            }
        }
    }

    // reduce (best,best2) across the 16 lanes of each row-group; write idx
    #pragma unroll
    for (int s = 0; s < 2; ++s) {
        #pragma unroll
        for (int off = 1; off < 16; off <<= 1) {
            #pragma unroll
            for (int r = 0; r < 4; ++r) {
                int ob  = __shfl_xor(best[s][r],  off);
                int ob2 = __shfl_xor(best2[s][r], off);
                int mn  = min(best[s][r], ob);
                int mx  = max(best[s][r], ob);
                best[s][r]  = mn;
                best2[s][r] = min(min(best2[s][r], ob2), mx);
            }
        }
        #pragma unroll
        for (int r = 0; r < 4; ++r) {
            if (col == r) {                    // static reg index, predicated write
                float d1 = __int_as_float(best[s][r]  & 0xFFFFFC00);
                float d2 = __int_as_float(best2[s][r] & 0xFFFFFC00);
                float fl = (d2 - d1 < MARGIN_P) ? FLAGF : 0.0f;
                idx_out[qbase + 16*s + 4*g + r] = (float)(best[s][r] & 1023) + fl;
            }
        }
    }
}

// ---------- K2: f64 rescore of flagged queries (precomputed consts, fast reduce) ----------
__global__ __launch_bounds__(256) void k_rescue(const float* __restrict__ inp,
                                                const float* __restrict__ emb,
                                                const double* __restrict__ wInvD,
                                                const double* __restrict__ wB2D,
                                                float* __restrict__ idx_out) {
    __shared__ int    lst[256];
    __shared__ int    cnt;
    __shared__ double xh[DIM];
    __shared__ double Ash;
    __shared__ double sdw[4];
    __shared__ int    siw[4];
    const int tid = threadIdx.x;
    const int lane = tid & 63, wv = tid >> 6;
    const int q0  = blockIdx.x * 256;

    if (tid == 0) cnt = 0;
    __syncthreads();
    if (idx_out[q0 + tid] >= FLAGF) { int s = atomicAdd(&cnt, 1); lst[s] = q0 + tid; }
    __syncthreads();
    const int n = cnt;

    for (int j = 0; j < n; ++j) {
        const int q = lst[j];
        if (tid < 64) {
            double xv = (double)inp[(size_t)q * DIM + tid];
            double s = xv * xv;
            #pragma unroll
            for (int off = 32; off; off >>= 1) s += __shfl_xor(s, off);
            double dn = fmax(sqrt(s), 1e-12);
            double h  = xv / dn;
            xh[tid] = h;
            double a = h * h;
            #pragma unroll
            for (int off = 32; off; off >>= 1) a += __shfl_xor(a, off);
            if (tid == 0) Ash = a;
        }
        __syncthreads();
        const double A = Ash;

        double bd = 1e300; int bi = 1 << 30;
        for (int c = tid; c < KC; c += 256) {          // 4 codes per thread
            const float* e = emb + (size_t)c * DIM;
            double dot = 0.0;
            #pragma unroll
            for (int i = 0; i < DIM; ++i) dot += xh[i] * (double)e[i];
            double d = (A + wB2D[c]) - 2.0 * (dot * wInvD[c]);
            if (d < bd || (d == bd && c < bi)) { bd = d; bi = c; }
        }
        #pragma unroll
        for (int off = 1; off < 64; off <<= 1) {       // 64-lane (d,i) min-reduce
            double od = __shfl_xor(bd, off);
            int    oi = __shfl_xor(bi, off);
            if (od < bd || (od == bd && oi < bi)) { bd = od; bi = oi; }
        }
        if (lane == 0) { sdw[wv] = bd; siw[wv] = bi; }
        __syncthreads();
        if (tid == 0) {
            double B = sdw[0]; int I = siw[0];
            #pragma unroll
            for (int i = 1; i < 4; ++i)
                if (sdw[i] < B || (sdw[i] == B && siw[i] < I)) { B = sdw[i]; I = siw[i]; }
            idx_out[q] = (float)I;                     // final, flag cleared
        }
        __syncthreads();
    }
}

// ---------- K3: gather (f32 out) + sum((q-f)^2) ----------
__global__ __launch_bounds__(256) void k_gather_loss(const float* __restrict__ inp,
                                                     const float* __restrict__ emb,
                                                     const float* __restrict__ idx_out,
                                                     float* __restrict__ qout,
                                                     float* __restrict__ loss) {
    const int gid = blockIdx.x * 256 + threadIdx.x;    // 524288 threads
    float lsum = 0.f;
    for (int e4 = gid; e4 < NQ * 16; e4 += 524288) {
        int   qi = e4 >> 4;
        int   d4 = e4 & 15;
        int   k  = ((int)idx_out[qi]) & (KC - 1);
        float4 qv = reinterpret_cast<const float4*>(emb + (size_t)k * DIM)[d4];
        float4 fv = reinterpret_cast<const float4*>(inp)[e4];
        float ux = qv.x - fv.x, uy = qv.y - fv.y, uz = qv.z - fv.z, uw = qv.w - fv.w;
        lsum += ux*ux + uy*uy + uz*uz + uw*uw;
        reinterpret_cast<float4*>(qout)[e4] = qv;
    }
    #pragma unroll
    for (int off = 32; off; off >>= 1) lsum += __shfl_xor(lsum, off);
    __shared__ float wsum[4];
    int wid = threadIdx.x >> 6, lane = threadIdx.x & 63;
    if (lane == 0) wsum[wid] = lsum;
    __syncthreads();
    if (threadIdx.x == 0)
        atomicAdd(loss, (wsum[0] + wsum[1]) + (wsum[2] + wsum[3]));
}

// ---------- K4: parallel histogram into ws counts ----------
__global__ __launch_bounds__(256) void k_hist(const float* __restrict__ idx_out,
                                              int* __restrict__ counts) {
    __shared__ int h[KC];
    const int tid = threadIdx.x;
    for (int i = tid; i < KC; i += 256) h[i] = 0;
    __syncthreads();
    const int qb = blockIdx.x * 2048;                  // grid 64 -> exactly NQ
    for (int i = tid; i < 2048; i += 256)
        atomicAdd(&h[((int)idx_out[qb + i]) & (KC - 1)], 1);
    __syncthreads();
    for (int i = tid; i < KC; i += 256) {
        int v = h[i];
        if (v) atomicAdd(&counts[i], v);
    }
}

// ---------- K5: perplexity / usage / vq_loss ----------
__global__ __launch_bounds__(1024) void k_stats2(const int* __restrict__ counts,
                                                 float* __restrict__ out3) {
    int t = threadIdx.x;
    int c = counts[t];
    float p    = (float)c * (1.0f / (float)NQ);
    float ent  = p * logf(p + 1e-10f);
    float used = (c > 0) ? 1.0f : 0.0f;
    #pragma unroll
    for (int off = 32; off; off >>= 1) {
        ent  += __shfl_xor(ent, off);
        used += __shfl_xor(used, off);
    }
    __shared__ float se[16], su[16];
    int w = t >> 6, l = t & 63;
    if (l == 0) { se[w] = ent; su[w] = used; }
    __syncthreads();
    if (t == 0) {
        float E = 0.f, U = 0.f;
        #pragma unroll
        for (int i = 0; i < 16; ++i) { E += se[i]; U += su[i]; }
        float L = out3[0];                             // loss accumulated here
        out3[0] = L * 1.25f / 8388608.0f;              // vq_loss (q + 0.25*e)
        out3[1] = expf(-E);                            // perplexity
        out3[2] = U * (1.0f / 1024.0f);                // codebook_usage
    }
}

// ---------- launch ----------
// d_out (f32, 8519683): [0,8388608) quantized | [8388608,8519680) idx | 3 scalars
// d_ws: counts[1024]@0 | wB u16[131072]@4096 | wE2p f32[1024]@266240
//       | wInvD f64[1024]@270336 | wB2D f64[1024]@278528   (total 286720 B)
extern "C" void kernel_launch(void* const* d_in, const int* in_sizes, int n_in,
                              void* d_out, int out_size, void* d_ws, size_t ws_size,
                              hipStream_t stream) {
    const float* inp = (const float*)d_in[0];   // [32,4096,64] f32
    const float* emb = (const float*)d_in[1];   // [1024,64] f32

    float* qout    = (float*)d_out;
    float* idx_out = (float*)d_out + 8388608;
    float* out3    = (float*)d_out + 8519680;

    int*            counts = (int*)d_ws;
    unsigned short* wB     = (unsigned short*)((char*)d_ws + 4096);
    float*          wE2p   = (float*)((char*)d_ws + 266240);
    double*         wInvD  = (double*)((char*)d_ws + 270336);
    double*         wB2D   = (double*)((char*)d_ws + 278528);

    hipMemsetAsync(d_ws, 0, 4096, stream);      // counts
    hipMemsetAsync(out3, 0, 4, stream);         // loss accumulator
    hipLaunchKernelGGL(k_prep,        dim3(4),    dim3(256),  0, stream,
                       emb, wB, wE2p, wInvD, wB2D);
    hipLaunchKernelGGL(k_assign,      dim3(1024), dim3(256),  0, stream,
                       inp, wB, wE2p, idx_out);
    hipLaunchKernelGGL(k_rescue,      dim3(512),  dim3(256),  0, stream,
                       inp, emb, wInvD, wB2D, idx_out);
    hipLaunchKernelGGL(k_gather_loss, dim3(2048), dim3(256),  0, stream,
                       inp, emb, idx_out, qout, out3);
    hipLaunchKernelGGL(k_hist,        dim3(64),   dim3(256),  0, stream, idx_out, counts);
    hipLaunchKernelGGL(k_stats2,      dim3(1),    dim3(1024), 0, stream, counts, out3);
}

// Round 7
// 169.652 us; speedup vs baseline: 5.4706x; 1.3341x over previous
//
#include <hip/hip_runtime.h>
#include <hip/hip_bf16.h>

#define NQ       131072     // 32*4096 queries
#define KC       1024       // codes
#define DIM      64
#define MARGIN_P 6.5e-4f    // packed-gap margin: 4e-4 true + 2*2.44e-4 quantization
#define RGRID    2048       // rescue grid (blocks); >= worst realistic flag count

typedef __attribute__((ext_vector_type(8))) short  s8bf;   // 8 bf16 (4 VGPRs)
typedef __attribute__((ext_vector_type(4))) float  f32x4;  // MFMA acc

union BF8 { s8bf v; unsigned short u[8]; };

__device__ __forceinline__ unsigned short f2bf_u(float f) {
    union { __hip_bfloat16 h; unsigned short u; } cv;
    cv.h = __float2bfloat16(f);
    return cv.u;
}
__device__ __forceinline__ float bfu2f(unsigned short u) {
    union { __hip_bfloat16 h; unsigned short u; } cv;
    cv.u = u;
    return __bfloat162float(cv.h);
}
__device__ __forceinline__ void gl_lds16(const float4* g, float4* l) {
    __builtin_amdgcn_global_load_lds(
        (const __attribute__((address_space(1))) unsigned int*)g,
        (__attribute__((address_space(3))) unsigned int*)l, 16, 0, 0);
}

// ---------- K0: prep codes -> bf16 hi/lo B-frags + e2p (f32) + f64 rescue consts ----------
__global__ __launch_bounds__(256) void k_prep(const float* __restrict__ emb,
                                              unsigned short* __restrict__ wB,
                                              float* __restrict__ wE2p,
                                              double* __restrict__ wInvD,
                                              double* __restrict__ wB2D) {
    int c = blockIdx.x * 256 + threadIdx.x;    // 4 blocks -> 1024 codes
    if (c >= KC) return;
    float e[DIM];
    const float4* ep = reinterpret_cast<const float4*>(emb + (size_t)c * DIM);
    #pragma unroll
    for (int i = 0; i < 16; ++i) {
        float4 t = ep[i];
        e[4*i+0] = t.x; e[4*i+1] = t.y; e[4*i+2] = t.z; e[4*i+3] = t.w;
    }
    float s = 0.f;
    #pragma unroll
    for (int i = 0; i < DIM; ++i) s += e[i] * e[i];
    float inv = 1.0f / fmaxf(sqrtf(s), 1e-12f);
    float e2 = 0.f;
    const int t = c >> 4, col = c & 15;
    #pragma unroll
    for (int k = 0; k < DIM; ++k) {
        float h = e[k] * inv;
        e2 += h * h;
        unsigned short hi = f2bf_u(h);
        unsigned short lo = f2bf_u(h - bfu2f(hi));
        int s_ = k >> 5, g = (k >> 3) & 3, j = k & 7;
        int ln = col + 16 * g;
        wB[((t*4 + s_*2 + 0) * 64 + ln) * 8 + j] = hi;
        wB[((t*4 + s_*2 + 1) * 64 + ln) * 8 + j] = lo;
    }
    wE2p[c] = e2 + 2.0f;                       // pre-biased for positive pack
    double sd = 0.0;
    #pragma unroll
    for (int i = 0; i < DIM; ++i) sd += (double)e[i] * (double)e[i];
    double invd = 1.0 / fmax(sqrt(sd), 1e-12);
    wInvD[c] = invd;
    wB2D[c]  = sd * invd * invd;
}

// ---------- K1: MFMA distances + packed-int argmin + global flag append ----------
// block = 256 thr (4 waves); wave handles 32 queries x all 1024 codes
__global__ __launch_bounds__(256) void k_assign(const float* __restrict__ inp,
                                                const unsigned short* __restrict__ wB,
                                                const float* __restrict__ wE2p,
                                                float* __restrict__ idx_out,
                                                int* __restrict__ flag_list,
                                                int* __restrict__ nflag) {
    __shared__ s8bf  Bt[2048];     // 32 KB: chunk = 8 tiles x 4 frags x 64 lanes
    __shared__ float e2ps[KC];     // 4 KB (e2+2)
    const int tid  = threadIdx.x;
    const int lane = tid & 63, wv = tid >> 6;
    const int col  = lane & 15, g  = lane >> 4;
    const int qbase = blockIdx.x * 128 + wv * 32;

    for (int i = tid; i < KC; i += 256) e2ps[i] = wE2p[i];

    BF8 ah[2][2], al[2][2];
    #pragma unroll
    for (int s = 0; s < 2; ++s) {
        const float4* q4 = reinterpret_cast<const float4*>(inp + (size_t)(qbase + 16*s + col) * DIM);
        float4 xa = q4[2*g], xb = q4[2*g + 1], ya = q4[8 + 2*g], yb = q4[9 + 2*g];
        float x[16] = { xa.x, xa.y, xa.z, xa.w, xb.x, xb.y, xb.z, xb.w,
                        ya.x, ya.y, ya.z, ya.w, yb.x, yb.y, yb.z, yb.w };
        float sq = 0.f;
        #pragma unroll
        for (int i = 0; i < 16; ++i) sq += x[i] * x[i];
        sq += __shfl_xor(sq, 16);
        sq += __shfl_xor(sq, 32);
        float inv = 1.0f / fmaxf(sqrtf(sq), 1e-12f);
        #pragma unroll
        for (int i = 0; i < 8; ++i) {
            float h0 = x[i] * inv, h1 = x[8 + i] * inv;
            unsigned short hi0 = f2bf_u(h0);
            unsigned short hi1 = f2bf_u(h1);
            ah[s][0].u[i] = hi0;  al[s][0].u[i] = f2bf_u(h0 - bfu2f(hi0));
            ah[s][1].u[i] = hi1;  al[s][1].u[i] = f2bf_u(h1 - bfu2f(hi1));
        }
    }

    int best[2][4], best2[2][4];
    #pragma unroll
    for (int s = 0; s < 2; ++s)
        #pragma unroll
        for (int r = 0; r < 4; ++r) { best[s][r] = 0x7FFFFFFF; best2[s][r] = 0x7FFFFFFF; }

    for (int ch = 0; ch < 8; ++ch) {           // 8 chunks of 128 codes
        __syncthreads();
        const float4* src = reinterpret_cast<const float4*>(wB) + (size_t)ch * 2048;
        float4* dst = reinterpret_cast<float4*>(Bt);
        #pragma unroll
        for (int i = 0; i < 8; ++i) {
            int idx = i * 256 + tid;
            gl_lds16(&src[idx], &dst[idx]);    // linear: base + lane*16 (m97 pattern)
        }
        __syncthreads();                       // drains vmcnt before use

        for (int nt = 0; nt < 8; ++nt) {       // 8 tiles of 16 codes
            s8bf bh0 = Bt[(nt*4 + 0) * 64 + lane];
            s8bf bl0 = Bt[(nt*4 + 1) * 64 + lane];
            s8bf bh1 = Bt[(nt*4 + 2) * 64 + lane];
            s8bf bl1 = Bt[(nt*4 + 3) * 64 + lane];
            const int code = ch * 128 + nt * 16 + col;
            const float e2p = e2ps[code];
            #pragma unroll
            for (int s = 0; s < 2; ++s) {
                f32x4 acc = {0.f, 0.f, 0.f, 0.f};
                acc = __builtin_amdgcn_mfma_f32_16x16x32_bf16(ah[s][0].v, bh0, acc, 0, 0, 0);
                acc = __builtin_amdgcn_mfma_f32_16x16x32_bf16(ah[s][1].v, bh1, acc, 0, 0, 0);
                acc = __builtin_amdgcn_mfma_f32_16x16x32_bf16(ah[s][0].v, bl0, acc, 0, 0, 0);
                acc = __builtin_amdgcn_mfma_f32_16x16x32_bf16(ah[s][1].v, bl1, acc, 0, 0, 0);
                acc = __builtin_amdgcn_mfma_f32_16x16x32_bf16(al[s][0].v, bh0, acc, 0, 0, 0);
                acc = __builtin_amdgcn_mfma_f32_16x16x32_bf16(al[s][1].v, bh1, acc, 0, 0, 0);
                #pragma unroll
                for (int r = 0; r < 4; ++r) {
                    float dp = fmaf(-2.0f, acc[r], e2p);          // in (0.9, 5.1) > 0
                    int p = (__float_as_int(dp) & 0xFFFFFC00) | code;
                    int mn = min(best[s][r], p);
                    int mx = max(best[s][r], p);
                    best[s][r]  = mn;
                    best2[s][r] = min(best2[s][r], mx);
                }
            }
        }
    }

    #pragma unroll
    for (int s = 0; s < 2; ++s) {
        #pragma unroll
        for (int off = 1; off < 16; off <<= 1) {
            #pragma unroll
            for (int r = 0; r < 4; ++r) {
                int ob  = __shfl_xor(best[s][r],  off);
                int ob2 = __shfl_xor(best2[s][r], off);
                int mn  = min(best[s][r], ob);
                int mx  = max(best[s][r], ob);
                best[s][r]  = mn;
                best2[s][r] = min(min(best2[s][r], ob2), mx);
            }
        }
        #pragma unroll
        for (int r = 0; r < 4; ++r) {
            if (col == r) {                    // owner lane for this query row
                int   q  = qbase + 16*s + 4*g + r;
                float d1 = __int_as_float(best[s][r]  & 0xFFFFFC00);
                float d2 = __int_as_float(best2[s][r] & 0xFFFFFC00);
                idx_out[q] = (float)(best[s][r] & 1023);
                if (d2 - d1 < MARGIN_P) {      // ambiguous -> global rescue list
                    int slot = atomicAdd(nflag, 1);
                    flag_list[slot] = q;
                }
            }
        }
    }
}

// ---------- K2: f64 rescore, block-per-flagged-query via global list ----------
__global__ __launch_bounds__(256) void k_rescue(const float* __restrict__ inp,
                                                const float* __restrict__ emb,
                                                const double* __restrict__ wInvD,
                                                const double* __restrict__ wB2D,
                                                const int* __restrict__ flag_list,
                                                const int* __restrict__ nflag,
                                                float* __restrict__ idx_out) {
    __shared__ double xh[DIM];
    __shared__ double Ash;
    __shared__ double sdw[4];
    __shared__ int    siw[4];
    const int tid = threadIdx.x;
    const int lane = tid & 63, wv = tid >> 6;
    const int n = *nflag;

    for (int j = blockIdx.x; j < n; j += gridDim.x) {   // uniform trip per block
        const int q = flag_list[j];
        if (tid < 64) {
            double xv = (double)inp[(size_t)q * DIM + tid];
            double s = xv * xv;
            #pragma unroll
            for (int off = 32; off; off >>= 1) s += __shfl_xor(s, off);
            double dn = fmax(sqrt(s), 1e-12);
            double h  = xv / dn;
            xh[tid] = h;
            double a = h * h;
            #pragma unroll
            for (int off = 32; off; off >>= 1) a += __shfl_xor(a, off);
            if (tid == 0) Ash = a;
        }
        __syncthreads();
        const double A = Ash;

        double bd = 1e300; int bi = 1 << 30;
        for (int c = tid; c < KC; c += 256) {          // 4 codes per thread
            const float* e = emb + (size_t)c * DIM;
            double dot = 0.0;
            #pragma unroll
            for (int i = 0; i < DIM; ++i) dot += xh[i] * (double)e[i];
            double d = (A + wB2D[c]) - 2.0 * (dot * wInvD[c]);
            if (d < bd || (d == bd && c < bi)) { bd = d; bi = c; }
        }
        #pragma unroll
        for (int off = 1; off < 64; off <<= 1) {       // 64-lane (d,i) min-reduce
            double od = __shfl_xor(bd, off);
            int    oi = __shfl_xor(bi, off);
            if (od < bd || (od == bd && oi < bi)) { bd = od; bi = oi; }
        }
        if (lane == 0) { sdw[wv] = bd; siw[wv] = bi; }
        __syncthreads();
        if (tid == 0) {
            double B = sdw[0]; int I = siw[0];
            #pragma unroll
            for (int i = 1; i < 4; ++i)
                if (sdw[i] < B || (sdw[i] == B && siw[i] < I)) { B = sdw[i]; I = siw[i]; }
            idx_out[q] = (float)I;                     // final
        }
        __syncthreads();
    }
}

// ---------- K3: gather (f32 out) + sum((q-f)^2) ----------
__global__ __launch_bounds__(256) void k_gather_loss(const float* __restrict__ inp,
                                                     const float* __restrict__ emb,
                                                     const float* __restrict__ idx_out,
                                                     float* __restrict__ qout,
                                                     float* __restrict__ loss) {
    const int gid = blockIdx.x * 256 + threadIdx.x;    // 524288 threads
    float lsum = 0.f;
    for (int e4 = gid; e4 < NQ * 16; e4 += 524288) {
        int   qi = e4 >> 4;
        int   d4 = e4 & 15;
        int   k  = ((int)idx_out[qi]) & (KC - 1);
        float4 qv = reinterpret_cast<const float4*>(emb + (size_t)k * DIM)[d4];
        float4 fv = reinterpret_cast<const float4*>(inp)[e4];
        float ux = qv.x - fv.x, uy = qv.y - fv.y, uz = qv.z - fv.z, uw = qv.w - fv.w;
        lsum += ux*ux + uy*uy + uz*uz + uw*uw;
        reinterpret_cast<float4*>(qout)[e4] = qv;
    }
    #pragma unroll
    for (int off = 32; off; off >>= 1) lsum += __shfl_xor(lsum, off);
    __shared__ float wsum[4];
    int wid = threadIdx.x >> 6, lane = threadIdx.x & 63;
    if (lane == 0) wsum[wid] = lsum;
    __syncthreads();
    if (threadIdx.x == 0)
        atomicAdd(loss, (wsum[0] + wsum[1]) + (wsum[2] + wsum[3]));
}

// ---------- K4: parallel histogram into ws counts ----------
__global__ __launch_bounds__(256) void k_hist(const float* __restrict__ idx_out,
                                              int* __restrict__ counts) {
    __shared__ int h[KC];
    const int tid = threadIdx.x;
    for (int i = tid; i < KC; i += 256) h[i] = 0;
    __syncthreads();
    const int qb = blockIdx.x * 2048;                  // grid 64 -> exactly NQ
    for (int i = tid; i < 2048; i += 256)
        atomicAdd(&h[((int)idx_out[qb + i]) & (KC - 1)], 1);
    __syncthreads();
    for (int i = tid; i < KC; i += 256) {
        int v = h[i];
        if (v) atomicAdd(&counts[i], v);
    }
}

// ---------- K5: perplexity / usage / vq_loss ----------
__global__ __launch_bounds__(1024) void k_stats2(const int* __restrict__ counts,
                                                 float* __restrict__ out3) {
    int t = threadIdx.x;
    int c = counts[t];
    float p    = (float)c * (1.0f / (float)NQ);
    float ent  = p * logf(p + 1e-10f);
    float used = (c > 0) ? 1.0f : 0.0f;
    #pragma unroll
    for (int off = 32; off; off >>= 1) {
        ent  += __shfl_xor(ent, off);
        used += __shfl_xor(used, off);
    }
    __shared__ float se[16], su[16];
    int w = t >> 6, l = t & 63;
    if (l == 0) { se[w] = ent; su[w] = used; }
    __syncthreads();
    if (t == 0) {
        float E = 0.f, U = 0.f;
        #pragma unroll
        for (int i = 0; i < 16; ++i) { E += se[i]; U += su[i]; }
        float L = out3[0];                             // loss accumulated here
        out3[0] = L * 1.25f / 8388608.0f;              // vq_loss (q + 0.25*e)
        out3[1] = expf(-E);                            // perplexity
        out3[2] = U * (1.0f / 1024.0f);                // codebook_usage
    }
}

// ---------- launch ----------
// d_out (f32, 8519683): [0,8388608) quantized | [8388608,8519680) idx | 3 scalars
// flag_list lives in the QUANTIZED region (consumed by k_rescue, then fully
// overwritten by k_gather_loss — stream-ordered). d_ws layout:
//   counts[1024]@0 | wB u16[131072]@4096 | wE2p f32[1024]@266240
//   | wInvD f64[1024]@270336 | wB2D f64[1024]@278528 | nflag@286720
extern "C" void kernel_launch(void* const* d_in, const int* in_sizes, int n_in,
                              void* d_out, int out_size, void* d_ws, size_t ws_size,
                              hipStream_t stream) {
    const float* inp = (const float*)d_in[0];   // [32,4096,64] f32
    const float* emb = (const float*)d_in[1];   // [1024,64] f32

    float* qout      = (float*)d_out;
    int*   flag_list = (int*)d_out;             // aliases qout (see note)
    float* idx_out   = (float*)d_out + 8388608;
    float* out3      = (float*)d_out + 8519680;

    int*            counts = (int*)d_ws;
    unsigned short* wB     = (unsigned short*)((char*)d_ws + 4096);
    float*          wE2p   = (float*)((char*)d_ws + 266240);
    double*         wInvD  = (double*)((char*)d_ws + 270336);
    double*         wB2D   = (double*)((char*)d_ws + 278528);
    int*            nflag  = (int*)((char*)d_ws + 286720);

    hipMemsetAsync(d_ws, 0, 4096, stream);      // counts
    hipMemsetAsync(nflag, 0, 4, stream);        // flag counter
    hipMemsetAsync(out3, 0, 4, stream);         // loss accumulator
    hipLaunchKernelGGL(k_prep,        dim3(4),     dim3(256),  0, stream,
                       emb, wB, wE2p, wInvD, wB2D);
    hipLaunchKernelGGL(k_assign,      dim3(1024),  dim3(256),  0, stream,
                       inp, wB, wE2p, idx_out, flag_list, nflag);
    hipLaunchKernelGGL(k_rescue,      dim3(RGRID), dim3(256),  0, stream,
                       inp, emb, wInvD, wB2D, flag_list, nflag, idx_out);
    hipLaunchKernelGGL(k_gather_loss, dim3(2048),  dim3(256),  0, stream,
                       inp, emb, idx_out, qout, out3);
    hipLaunchKernelGGL(k_hist,        dim3(64),    dim3(256),  0, stream, idx_out, counts);
    hipLaunchKernelGGL(k_stats2,      dim3(1),     dim3(1024), 0, stream, counts, out3);
}